// Round 1
// baseline (48.893 us; speedup 1.0000x reference)
//
#include <hip/hip_runtime.h>
#include <math.h>

#define NPTS   32
#define UNITS  64
#define PTOT   40000
#define NPAIRS (PTOT / 2)          // 20000
#define SBLOCKS 1250
#define WPB     4                  // waves per block (256 threads)
#define TOTW    (SBLOCKS * WPB)    // 5000 waves
#define PPW     (NPAIRS / TOTW)    // 4 pillar-pairs per wave (exact)

// x = b + f0*wp0 + f1*wp1 + f2*wp2 + f3*wp3, per lane(=unit)
// wp folds W rows: wp0=W0+W4+W7, wp1=W1+W5+W8, wp2=W2+W6, wp3=W3
// b = -(m0*W4 + m1*W5 + m2*W6 + cx*W7 + cy*W8)

__global__ __launch_bounds__(256)
void pfn_stats(const float* __restrict__ feat,
               const int*   __restrict__ nvox,
               const int*   __restrict__ coors,
               const float* __restrict__ Wm,
               float*       __restrict__ partials)
{
    __shared__ float sf[WPB][2][NPTS][4];
    __shared__ float ps[WPB][128];

    const int tid  = threadIdx.x;
    const int wave = tid >> 6, lane = tid & 63;
    const int gwave = blockIdx.x * WPB + wave;
    const int half = lane >> 5, pt = lane & 31;

    const float w4 = Wm[4 * UNITS + lane], w5 = Wm[5 * UNITS + lane], w6 = Wm[6 * UNITS + lane];
    const float w7 = Wm[7 * UNITS + lane], w8 = Wm[8 * UNITS + lane];
    const float wp0 = Wm[0 * UNITS + lane] + w4 + w7;
    const float wp1 = Wm[1 * UNITS + lane] + w5 + w8;
    const float wp2 = Wm[2 * UNITS + lane] + w6;
    const float wp3 = Wm[3 * UNITS + lane];

    float lsum = 0.f, lsq = 0.f;

    for (int it = 0; it < PPW; ++it) {
        const int pair = it * TOTW + gwave;
        const int p0 = pair * 2;
        const float4 f4 = *reinterpret_cast<const float4*>(feat + (size_t)p0 * (NPTS * 4) + lane * 4);
        // per-half (32-lane) xyz sums for points_mean (sums over ALL 32 points, per reference)
        float sx = f4.x, sy = f4.y, sz = f4.z;
        #pragma unroll
        for (int off = 1; off < 32; off <<= 1) {
            sx += __shfl_xor(sx, off);
            sy += __shfl_xor(sy, off);
            sz += __shfl_xor(sz, off);
        }
        __syncthreads();                                   // WAR vs previous iter's reads
        *reinterpret_cast<float4*>(&sf[wave][half][pt][0]) = f4;
        __syncthreads();                                   // staging visible

        #pragma unroll
        for (int pp = 0; pp < 2; ++pp) {
            const int p = p0 + pp;
            int nv = nvox[p];
            nv = nv < 1 ? 1 : (nv > NPTS ? NPTS : nv);
            const float inv_nv = 1.f / (float)nv;
            const float m0 = __shfl(sx, pp * 32) * inv_nv;
            const float m1 = __shfl(sy, pp * 32) * inv_nv;
            const float m2 = __shfl(sz, pp * 32) * inv_nv;
            const float cx = (float)coors[p * 4 + 3] * 0.2f + 0.1f;
            const float cy = (float)coors[p * 4 + 2] * 0.2f + (-39.9f);
            const float b = -(m0 * w4 + m1 * w5 + m2 * w6 + cx * w7 + cy * w8);
            for (int n = 0; n < nv; ++n) {                 // masked points contribute exactly 0
                const float4 f = *reinterpret_cast<const float4*>(&sf[wave][pp][n][0]);
                const float x = b + f.x * wp0 + f.y * wp1 + f.z * wp2 + f.w * wp3;
                lsum += x;
                lsq = fmaf(x, x, lsq);
            }
        }
    }
    ps[wave][lane]      = lsum;
    ps[wave][64 + lane] = lsq;
    __syncthreads();
    if (tid < 128)
        partials[blockIdx.x * 128 + tid] = ps[0][tid] + ps[1][tid] + ps[2][tid] + ps[3][tid];
}

__global__ __launch_bounds__(256)
void pfn_finalize(const float* __restrict__ partials,
                  const float* __restrict__ gamma,
                  const float* __restrict__ beta,
                  float*       __restrict__ ss)
{
    const int u = blockIdx.x;   // 0..63
    const int t = threadIdx.x;  // 0..255
    double aS = 0.0, aQ = 0.0;
    for (int b = t; b < SBLOCKS; b += 256) {
        aS += (double)partials[b * 128 + u];
        aQ += (double)partials[b * 128 + 64 + u];
    }
    __shared__ double sS[256], sQ[256];
    sS[t] = aS; sQ[t] = aQ;
    __syncthreads();
    for (int s = 128; s > 0; s >>= 1) {
        if (t < s) { sS[t] += sS[t + s]; sQ[t] += sQ[t + s]; }
        __syncthreads();
    }
    if (t == 0) {
        const double inv_pn = 1.0 / ((double)PTOT * (double)NPTS);
        const double mean = sS[0] * inv_pn;
        const double var  = sQ[0] * inv_pn - mean * mean;
        const float scale = gamma[u] * (float)(1.0 / sqrt(var + 1e-3));
        const float shift = beta[u] - (float)mean * scale;
        ss[u]      = scale;
        ss[64 + u] = shift;
    }
}

__global__ __launch_bounds__(256)
void pfn_out(const float* __restrict__ feat,
             const int*   __restrict__ nvox,
             const int*   __restrict__ coors,
             const float* __restrict__ Wm,
             const float* __restrict__ ss,
             float*       __restrict__ out)
{
    __shared__ float sf[WPB][2][NPTS][4];

    const int tid  = threadIdx.x;
    const int wave = tid >> 6, lane = tid & 63;
    const int gwave = blockIdx.x * WPB + wave;
    const int half = lane >> 5, pt = lane & 31;

    const float w4 = Wm[4 * UNITS + lane], w5 = Wm[5 * UNITS + lane], w6 = Wm[6 * UNITS + lane];
    const float w7 = Wm[7 * UNITS + lane], w8 = Wm[8 * UNITS + lane];
    const float wp0 = Wm[0 * UNITS + lane] + w4 + w7;
    const float wp1 = Wm[1 * UNITS + lane] + w5 + w8;
    const float wp2 = Wm[2 * UNITS + lane] + w6;
    const float wp3 = Wm[3 * UNITS + lane];
    const float scale = ss[lane], shift = ss[64 + lane];

    for (int it = 0; it < PPW; ++it) {
        const int pair = it * TOTW + gwave;
        const int p0 = pair * 2;
        const float4 f4 = *reinterpret_cast<const float4*>(feat + (size_t)p0 * (NPTS * 4) + lane * 4);
        float sx = f4.x, sy = f4.y, sz = f4.z;
        #pragma unroll
        for (int off = 1; off < 32; off <<= 1) {
            sx += __shfl_xor(sx, off);
            sy += __shfl_xor(sy, off);
            sz += __shfl_xor(sz, off);
        }
        __syncthreads();
        *reinterpret_cast<float4*>(&sf[wave][half][pt][0]) = f4;
        __syncthreads();

        #pragma unroll
        for (int pp = 0; pp < 2; ++pp) {
            const int p = p0 + pp;
            int nv = nvox[p];
            nv = nv < 1 ? 1 : (nv > NPTS ? NPTS : nv);
            const float inv_nv = 1.f / (float)nv;
            const float m0 = __shfl(sx, pp * 32) * inv_nv;
            const float m1 = __shfl(sy, pp * 32) * inv_nv;
            const float m2 = __shfl(sz, pp * 32) * inv_nv;
            const float cx = (float)coors[p * 4 + 3] * 0.2f + 0.1f;
            const float cy = (float)coors[p * 4 + 2] * 0.2f + (-39.9f);
            const float b = -(m0 * w4 + m1 * w5 + m2 * w6 + cx * w7 + cy * w8);
            float mx = -3.4e38f, mn = 3.4e38f;
            for (int n = 0; n < nv; ++n) {
                const float4 f = *reinterpret_cast<const float4*>(&sf[wave][pp][n][0]);
                const float x = b + f.x * wp0 + f.y * wp1 + f.z * wp2 + f.w * wp3;
                mx = fmaxf(mx, x);
                mn = fminf(mn, x);
            }
            // max over n of relu(scale*x+shift): monotone => use extreme of x by sign(scale);
            // padded points (n>=nv) have x=0 -> candidate shift.
            float y = (scale >= 0.f) ? mx : mn;
            y = fmaf(y, scale, shift);
            if (nv < NPTS) y = fmaxf(y, shift);
            out[(size_t)p * UNITS + lane] = fmaxf(y, 0.f);
        }
    }
}

extern "C" void kernel_launch(void* const* d_in, const int* in_sizes, int n_in,
                              void* d_out, int out_size, void* d_ws, size_t ws_size,
                              hipStream_t stream)
{
    const float* feat  = (const float*)d_in[0];
    const int*   nvox  = (const int*)d_in[1];
    const int*   coors = (const int*)d_in[2];
    const float* Wm    = (const float*)d_in[3];
    const float* gamma = (const float*)d_in[4];
    const float* beta  = (const float*)d_in[5];
    float* out = (float*)d_out;

    float* partials = (float*)d_ws;                 // SBLOCKS*128 floats = 640 KB
    float* ss       = partials + SBLOCKS * 128;     // 128 floats (scale, shift)

    pfn_stats<<<SBLOCKS, 256, 0, stream>>>(feat, nvox, coors, Wm, partials);
    pfn_finalize<<<UNITS, 256, 0, stream>>>(partials, gamma, beta, ss);
    pfn_out<<<SBLOCKS, 256, 0, stream>>>(feat, nvox, coors, Wm, ss, out);
}

// Round 2
// 42.677 us; speedup vs baseline: 1.1456x; 1.1456x over previous
//
#include <hip/hip_runtime.h>
#include <math.h>

#define NPTS   32
#define UNITS  64
#define PTOT   40000
#define NPAIRS (PTOT / 2)          // 20000
#define SBLOCKS 1250
#define WPB     4                  // waves per block (256 threads)
#define TOTW    (SBLOCKS * WPB)    // 5000 waves
#define PPW     (NPAIRS / TOTW)    // 4 pillar-pairs per wave (exact)

// x[p,n,u] = b[p,u] + f0*wp0 + f1*wp1 + f2*wp2 + f3*wp3  (per lane = unit)
// wp folds W rows: wp0=W0+W4+W7, wp1=W1+W5+W8, wp2=W2+W6, wp3=W3
// b = -(m0*W4 + m1*W5 + m2*W6 + cx*W7 + cy*W8)

// Kernel A: single heavy pass. Produces per-(pillar,unit) {max,min} of x over
// valid points (float2 -> ws) and per-block BN partial sums (sum, sumsq).
__global__ __launch_bounds__(256)
void pfn_main(const float* __restrict__ feat,
              const int*   __restrict__ nvox,
              const int*   __restrict__ coors,
              const float* __restrict__ Wm,
              float2*      __restrict__ mxmn,
              float*       __restrict__ partials)
{
    __shared__ float4 sf[WPB][PPW][2][NPTS];   // wave-private staging: no barriers needed
    __shared__ float  ps[WPB][128];

    const int tid  = threadIdx.x;
    const int wave = tid >> 6, lane = tid & 63;
    const int gwave = blockIdx.x * WPB + wave;
    const int half = lane >> 5, pt = lane & 31;

    const float w4 = Wm[4 * UNITS + lane], w5 = Wm[5 * UNITS + lane], w6 = Wm[6 * UNITS + lane];
    const float w7 = Wm[7 * UNITS + lane], w8 = Wm[8 * UNITS + lane];
    const float wp0 = Wm[0 * UNITS + lane] + w4 + w7;
    const float wp1 = Wm[1 * UNITS + lane] + w5 + w8;
    const float wp2 = Wm[2 * UNITS + lane] + w6;
    const float wp3 = Wm[3 * UNITS + lane];

    // ---- prefetch: issue ALL global loads up-front ----
    float4 fv[PPW];
    int    nvv[2 * PPW];
    float  cxv[2 * PPW], cyv[2 * PPW];
    #pragma unroll
    for (int it = 0; it < PPW; ++it) {
        const int pair = it * TOTW + gwave;
        fv[it] = *reinterpret_cast<const float4*>(feat + (size_t)pair * (2 * NPTS * 4) + lane * 4);
        const int p0 = pair * 2;
        #pragma unroll
        for (int pp = 0; pp < 2; ++pp) {
            int nv = nvox[p0 + pp];
            nvv[2 * it + pp] = nv < 1 ? 1 : (nv > NPTS ? NPTS : nv);
            cxv[2 * it + pp] = (float)coors[(p0 + pp) * 4 + 3] * 0.2f + 0.1f;
            cyv[2 * it + pp] = (float)coors[(p0 + pp) * 4 + 2] * 0.2f + (-39.9f);
        }
    }

    float lsum = 0.f, lsq = 0.f;

    #pragma unroll
    for (int it = 0; it < PPW; ++it) {
        const int pair = it * TOTW + gwave;
        const int p0 = pair * 2;

        // stage to wave-private LDS (in-wave ordering via lgkmcnt; no __syncthreads)
        sf[wave][it][half][pt] = fv[it];

        // per-half xyz sums over all 32 points (reference sums unmasked)
        float sx = fv[it].x, sy = fv[it].y, sz = fv[it].z;
        #pragma unroll
        for (int off = 1; off < 32; off <<= 1) {
            sx += __shfl_xor(sx, off);
            sy += __shfl_xor(sy, off);
            sz += __shfl_xor(sz, off);
        }

        const int   nvA = nvv[2 * it],       nvB = nvv[2 * it + 1];
        const float iA  = 1.f / (float)nvA,  iB  = 1.f / (float)nvB;
        const float mA0 = __shfl(sx, 0)  * iA, mA1 = __shfl(sy, 0)  * iA, mA2 = __shfl(sz, 0)  * iA;
        const float mB0 = __shfl(sx, 32) * iB, mB1 = __shfl(sy, 32) * iB, mB2 = __shfl(sz, 32) * iB;
        const float bA = -(mA0 * w4 + mA1 * w5 + mA2 * w6 + cxv[2 * it] * w7 + cyv[2 * it] * w8);
        const float bB = -(mB0 * w4 + mB1 * w5 + mB2 * w6 + cxv[2 * it + 1] * w7 + cyv[2 * it + 1] * w8);

        float mxA = -3.4e38f, mnA = 3.4e38f, mxB = -3.4e38f, mnB = 3.4e38f;
        const int nmax = nvA > nvB ? nvA : nvB;
        for (int n = 0; n < nmax; ++n) {
            const float4 a  = sf[wave][it][0][n];   // broadcast reads (same addr all lanes)
            const float4 b4 = sf[wave][it][1][n];
            const float xA = fmaf(a.x,  wp0, fmaf(a.y,  wp1, fmaf(a.z,  wp2, fmaf(a.w,  wp3, bA))));
            const float xB = fmaf(b4.x, wp0, fmaf(b4.y, wp1, fmaf(b4.z, wp2, fmaf(b4.w, wp3, bB))));
            if (n < nvA) {
                lsum += xA; lsq = fmaf(xA, xA, lsq);
                mxA = fmaxf(mxA, xA); mnA = fminf(mnA, xA);
            }
            if (n < nvB) {
                lsum += xB; lsq = fmaf(xB, xB, lsq);
                mxB = fmaxf(mxB, xB); mnB = fminf(mnB, xB);
            }
        }
        mxmn[(size_t)p0 * UNITS + lane]       = make_float2(mxA, mnA);
        mxmn[(size_t)(p0 + 1) * UNITS + lane] = make_float2(mxB, mnB);
    }

    ps[wave][lane]      = lsum;
    ps[wave][64 + lane] = lsq;
    __syncthreads();
    if (tid < 128)
        partials[blockIdx.x * 128 + tid] = ps[0][tid] + ps[1][tid] + ps[2][tid] + ps[3][tid];
}

__global__ __launch_bounds__(256)
void pfn_finalize(const float* __restrict__ partials,
                  const float* __restrict__ gamma,
                  const float* __restrict__ beta,
                  float*       __restrict__ ss)
{
    const int u = blockIdx.x;   // 0..63
    const int t = threadIdx.x;  // 0..255
    double aS = 0.0, aQ = 0.0;
    for (int b = t; b < SBLOCKS; b += 256) {
        aS += (double)partials[b * 128 + u];
        aQ += (double)partials[b * 128 + 64 + u];
    }
    __shared__ double sS[256], sQ[256];
    sS[t] = aS; sQ[t] = aQ;
    __syncthreads();
    for (int s = 128; s > 0; s >>= 1) {
        if (t < s) { sS[t] += sS[t + s]; sQ[t] += sQ[t + s]; }
        __syncthreads();
    }
    if (t == 0) {
        const double inv_pn = 1.0 / ((double)PTOT * (double)NPTS);
        const double mean = sS[0] * inv_pn;
        const double var  = sQ[0] * inv_pn - mean * mean;
        const float scale = gamma[u] * (float)(1.0 / sqrt(var + 1e-3));
        const float shift = beta[u] - (float)mean * scale;
        ss[u]      = scale;
        ss[64 + u] = shift;
    }
}

// Kernel C: streaming apply. out[p,u] = relu(max_n(scale*x+shift)) using the
// precomputed per-(p,u) extremes; padded points contribute shift when nv<32.
#define CBLOCKS 5000
#define CSTRIDE (CBLOCKS * 256)    // 1,280,000 ; 2 iters covers 2,560,000 exactly

__global__ __launch_bounds__(256)
void pfn_apply(const float2* __restrict__ mxmn,
               const int*    __restrict__ nvox,
               const float*  __restrict__ ss,
               float*        __restrict__ out)
{
    const int u = threadIdx.x & 63;              // stride is a multiple of 64
    const float scale = ss[u], shift = ss[64 + u];
    int i = blockIdx.x * 256 + threadIdx.x;
    #pragma unroll
    for (int k = 0; k < 2; ++k, i += CSTRIDE) {
        const int p = i >> 6;
        const float2 m = mxmn[i];
        const int nv = nvox[p];
        float y = (scale >= 0.f) ? m.x : m.y;
        y = fmaf(y, scale, shift);
        if (nv < NPTS) y = fmaxf(y, shift);
        out[i] = fmaxf(y, 0.f);
    }
}

extern "C" void kernel_launch(void* const* d_in, const int* in_sizes, int n_in,
                              void* d_out, int out_size, void* d_ws, size_t ws_size,
                              hipStream_t stream)
{
    const float* feat  = (const float*)d_in[0];
    const int*   nvox  = (const int*)d_in[1];
    const int*   coors = (const int*)d_in[2];
    const float* Wm    = (const float*)d_in[3];
    const float* gamma = (const float*)d_in[4];
    const float* beta  = (const float*)d_in[5];
    float* out = (float*)d_out;

    float2* mxmn    = (float2*)d_ws;                         // P*U float2 = 20.48 MB
    float*  partials = (float*)(mxmn + (size_t)PTOT * UNITS); // SBLOCKS*128 floats
    float*  ss       = partials + SBLOCKS * 128;              // 128 floats

    pfn_main<<<SBLOCKS, 256, 0, stream>>>(feat, nvox, coors, Wm, mxmn, partials);
    pfn_finalize<<<UNITS, 256, 0, stream>>>(partials, gamma, beta, ss);
    pfn_apply<<<CBLOCKS, 256, 0, stream>>>(mxmn, nvox, ss, out);
}

// Round 3
// 42.207 us; speedup vs baseline: 1.1584x; 1.0111x over previous
//
#include <hip/hip_runtime.h>
#include <math.h>

#define NPTS   32
#define UNITS  64
#define PTOT   40000
#define NPAIRS (PTOT / 2)          // 20000
#define SBLOCKS 2500
#define WPB     4                  // waves per block (256 threads)
#define TOTW    (SBLOCKS * WPB)    // 10000 waves
#define PPW     (NPAIRS / TOTW)    // 2 pillar-pairs per wave (exact)

// x[p,n,u] = b[p,u] + f0*wp0 + f1*wp1 + f2*wp2 + f3*wp3  (per lane = unit)
// wp folds W rows: wp0=W0+W4+W7, wp1=W1+W5+W8, wp2=W2+W6, wp3=W3
// b = -(m0*W4 + m1*W5 + m2*W6 + cx*W7 + cy*W8)
// sg = sign(gamma[u]) is folded into all weights so the FMA chain yields
// x' = sg*x; we track max(x') and recover: ext = sg*max(x') = (sg>0?max:min)(x).

// Kernel A: single heavy pass. Produces per-(pillar,unit) sg-extreme of x over
// valid points (float -> ws) and per-block BN partial sums (sum, sumsq).
__global__ __launch_bounds__(256)
void pfn_main(const float* __restrict__ feat,
              const int*   __restrict__ nvox,
              const int*   __restrict__ coors,
              const float* __restrict__ Wm,
              const float* __restrict__ gamma,
              float*       __restrict__ xext,
              float*       __restrict__ partials)
{
    __shared__ float4 sf[WPB][PPW][2][NPTS];   // wave-private staging: no barriers needed
    __shared__ float  ps[WPB][128];

    const int tid  = threadIdx.x;
    const int wave = tid >> 6, lane = tid & 63;
    const int gwave = blockIdx.x * WPB + wave;
    const int half = lane >> 5, pt = lane & 31;

    const float sg  = (gamma[lane] >= 0.f) ? 1.f : -1.f;
    const float w4 = sg * Wm[4 * UNITS + lane], w5 = sg * Wm[5 * UNITS + lane];
    const float w6 = sg * Wm[6 * UNITS + lane], w7 = sg * Wm[7 * UNITS + lane];
    const float w8 = sg * Wm[8 * UNITS + lane];
    const float wp0 = sg * Wm[0 * UNITS + lane] + w4 + w7;
    const float wp1 = sg * Wm[1 * UNITS + lane] + w5 + w8;
    const float wp2 = sg * Wm[2 * UNITS + lane] + w6;
    const float wp3 = sg * Wm[3 * UNITS + lane];

    // prefetch the big feature loads for both pairs
    float4 fv[PPW];
    #pragma unroll
    for (int it = 0; it < PPW; ++it) {
        const int pair = it * TOTW + gwave;
        fv[it] = *reinterpret_cast<const float4*>(feat + (size_t)pair * (2 * NPTS * 4) + lane * 4);
    }

    float lsum = 0.f, lsq = 0.f;   // sums of x' = sg*x ; fixed up at the end

    #pragma unroll
    for (int it = 0; it < PPW; ++it) {
        const int pair = it * TOTW + gwave;
        const int p0 = pair * 2;

        // stage to wave-private LDS (in-wave ordering via lgkmcnt; no __syncthreads)
        sf[wave][it][half][pt] = fv[it];

        // per-half xyz sums over all 32 raw points (reference sums unmasked)
        float sx = fv[it].x, sy = fv[it].y, sz = fv[it].z;
        #pragma unroll
        for (int off = 1; off < 32; off <<= 1) {
            sx += __shfl_xor(sx, off);
            sy += __shfl_xor(sy, off);
            sz += __shfl_xor(sz, off);
        }

        int nvA = nvox[p0], nvB = nvox[p0 + 1];
        nvA = nvA < 1 ? 1 : (nvA > NPTS ? NPTS : nvA);
        nvB = nvB < 1 ? 1 : (nvB > NPTS ? NPTS : nvB);
        const float cxA = (float)coors[p0 * 4 + 3] * 0.2f + 0.1f;
        const float cyA = (float)coors[p0 * 4 + 2] * 0.2f + (-39.9f);
        const float cxB = (float)coors[p0 * 4 + 7] * 0.2f + 0.1f;
        const float cyB = (float)coors[p0 * 4 + 6] * 0.2f + (-39.9f);
        const float iA  = 1.f / (float)nvA,  iB  = 1.f / (float)nvB;
        const float mA0 = __shfl(sx, 0)  * iA, mA1 = __shfl(sy, 0)  * iA, mA2 = __shfl(sz, 0)  * iA;
        const float mB0 = __shfl(sx, 32) * iB, mB1 = __shfl(sy, 32) * iB, mB2 = __shfl(sz, 32) * iB;
        const float bA = -(mA0 * w4 + mA1 * w5 + mA2 * w6 + cxA * w7 + cyA * w8);
        const float bB = -(mB0 * w4 + mB1 * w5 + mB2 * w6 + cxB * w7 + cyB * w8);

        float mA = -3.4e38f, mB = -3.4e38f;
        const int nmax = nvA > nvB ? nvA : nvB;
        for (int n = 0; n < nmax; ++n) {
            const float4 a  = sf[wave][it][0][n];   // broadcast reads (same addr all lanes)
            const float4 b4 = sf[wave][it][1][n];
            const float xA = fmaf(a.x,  wp0, fmaf(a.y,  wp1, fmaf(a.z,  wp2, fmaf(a.w,  wp3, bA))));
            const float xB = fmaf(b4.x, wp0, fmaf(b4.y, wp1, fmaf(b4.z, wp2, fmaf(b4.w, wp3, bB))));
            if (n < nvA) {
                lsum += xA; lsq = fmaf(xA, xA, lsq);
                mA = fmaxf(mA, xA);
            }
            if (n < nvB) {
                lsum += xB; lsq = fmaf(xB, xB, lsq);
                mB = fmaxf(mB, xB);
            }
        }
        xext[(size_t)p0 * UNITS + lane]       = sg * mA;
        xext[(size_t)(p0 + 1) * UNITS + lane] = sg * mB;
    }

    ps[wave][lane]      = sg * lsum;   // Σx = sg * Σx'
    ps[wave][64 + lane] = lsq;         // x'^2 == x^2
    __syncthreads();
    if (tid < 128)
        partials[blockIdx.x * 128 + tid] = ps[0][tid] + ps[1][tid] + ps[2][tid] + ps[3][tid];
}

__global__ __launch_bounds__(256)
void pfn_finalize(const float* __restrict__ partials,
                  const float* __restrict__ gamma,
                  const float* __restrict__ beta,
                  float*       __restrict__ ss)
{
    const int u = blockIdx.x;   // 0..63
    const int t = threadIdx.x;  // 0..255
    double aS = 0.0, aQ = 0.0;
    for (int b = t; b < SBLOCKS; b += 256) {
        aS += (double)partials[b * 128 + u];
        aQ += (double)partials[b * 128 + 64 + u];
    }
    __shared__ double sS[256], sQ[256];
    sS[t] = aS; sQ[t] = aQ;
    __syncthreads();
    for (int s = 128; s > 0; s >>= 1) {
        if (t < s) { sS[t] += sS[t + s]; sQ[t] += sQ[t + s]; }
        __syncthreads();
    }
    if (t == 0) {
        const double inv_pn = 1.0 / ((double)PTOT * (double)NPTS);
        const double mean = sS[0] * inv_pn;
        const double var  = sQ[0] * inv_pn - mean * mean;
        const float scale = gamma[u] * (float)(1.0 / sqrt(var + 1e-3));
        const float shift = beta[u] - (float)mean * scale;
        ss[u]      = scale;
        ss[64 + u] = shift;
    }
}

// Kernel C: streaming apply. out[p,u] = relu over candidates:
//   scale*ext+shift (extreme of valid points, correct side via sign(gamma)),
//   shift (padded points exist when nv<32), 0 (relu floor).
#define CBLOCKS 2500
#define CSTRIDE (CBLOCKS * 256)    // 640,000 ; 4 iters covers 2,560,000 exactly

__global__ __launch_bounds__(256)
void pfn_apply(const float* __restrict__ xext,
               const int*   __restrict__ nvox,
               const float* __restrict__ ss,
               float*       __restrict__ out)
{
    const int u = threadIdx.x & 63;              // stride is a multiple of 64
    const float scale = ss[u], shift = ss[64 + u];
    int i = blockIdx.x * 256 + threadIdx.x;
    #pragma unroll
    for (int k = 0; k < 4; ++k, i += CSTRIDE) {
        const int p = i >> 6;
        const float e = xext[i];
        const int nv = nvox[p];
        const float base = (nv < NPTS) ? fmaxf(shift, 0.f) : 0.f;
        out[i] = fmaxf(fmaf(e, scale, shift), base);
    }
}

extern "C" void kernel_launch(void* const* d_in, const int* in_sizes, int n_in,
                              void* d_out, int out_size, void* d_ws, size_t ws_size,
                              hipStream_t stream)
{
    const float* feat  = (const float*)d_in[0];
    const int*   nvox  = (const int*)d_in[1];
    const int*   coors = (const int*)d_in[2];
    const float* Wm    = (const float*)d_in[3];
    const float* gamma = (const float*)d_in[4];
    const float* beta  = (const float*)d_in[5];
    float* out = (float*)d_out;

    float* xext     = (float*)d_ws;                            // P*U floats = 10.24 MB
    float* partials = xext + (size_t)PTOT * UNITS;             // SBLOCKS*128 floats
    float* ss       = partials + (size_t)SBLOCKS * 128;        // 128 floats

    pfn_main<<<SBLOCKS, 256, 0, stream>>>(feat, nvox, coors, Wm, gamma, xext, partials);
    pfn_finalize<<<UNITS, 256, 0, stream>>>(partials, gamma, beta, ss);
    pfn_apply<<<CBLOCKS, 256, 0, stream>>>(xext, nvox, ss, out);
}

// Round 4
// 34.730 us; speedup vs baseline: 1.4078x; 1.2153x over previous
//
#include <hip/hip_runtime.h>
#include <math.h>

#define NPTS   32
#define UNITS  64
#define PTOT   40000
#define NPAIRS (PTOT / 2)          // 20000
#define SBLOCKS 2500
#define WPB     4                  // waves per block (256 threads)
#define TOTW    (SBLOCKS * WPB)    // 10000 waves
#define PPW     (NPAIRS / TOTW)    // 2 pillar-pairs per wave (exact)

// x[p,n,u] = b[p,u] + f0*wp0 + f1*wp1 + f2*wp2 + f3*wp3  (per lane = unit)
// wp folds W rows: wp0=W0+W4+W7, wp1=W1+W5+W8, wp2=W2+W6, wp3=W3
// b = -(m0*W4 + m1*W5 + m2*W6 + cx*W7 + cy*W8)
// sg = sign(gamma[u]) folded into weights: chain yields x' = sg*x, track max(x').
// Inner loop reads points via WAVE-UNIFORM addresses (wave id readfirstlane-
// hoisted) -> compiler emits s_load; point data enters FMAs as scalar operands.

__global__ __launch_bounds__(256)
void pfn_main(const float* __restrict__ feat,
              const int*   __restrict__ nvox,
              const int*   __restrict__ coors,
              const float* __restrict__ Wm,
              const float* __restrict__ gamma,
              float*       __restrict__ xext,
              float*       __restrict__ partials)
{
    __shared__ float ps[WPB][128];

    const int tid  = threadIdx.x;
    const int lane = tid & 63;
    const int wave = __builtin_amdgcn_readfirstlane(tid >> 6);   // provably uniform
    const int gwave = blockIdx.x * WPB + wave;

    const float sg  = (gamma[lane] >= 0.f) ? 1.f : -1.f;
    const float w4 = sg * Wm[4 * UNITS + lane], w5 = sg * Wm[5 * UNITS + lane];
    const float w6 = sg * Wm[6 * UNITS + lane], w7 = sg * Wm[7 * UNITS + lane];
    const float w8 = sg * Wm[8 * UNITS + lane];
    const float wp0 = sg * Wm[0 * UNITS + lane] + w4 + w7;
    const float wp1 = sg * Wm[1 * UNITS + lane] + w5 + w8;
    const float wp2 = sg * Wm[2 * UNITS + lane] + w6;
    const float wp3 = sg * Wm[3 * UNITS + lane];

    float lsum = 0.f, lsq = 0.f;   // sums of x' = sg*x ; fixed up at the end

    #pragma unroll
    for (int it = 0; it < PPW; ++it) {
        const int pair = it * TOTW + gwave;   // uniform
        const int p0 = pair * 2;              // uniform

        // vector load of both pillars' points (1 KB/wave, coalesced) for means
        const float4 f4 = *reinterpret_cast<const float4*>(feat + (size_t)pair * 256 + lane * 4);
        float sx = f4.x, sy = f4.y, sz = f4.z;
        #pragma unroll
        for (int off = 1; off < 32; off <<= 1) {
            sx += __shfl_xor(sx, off);
            sy += __shfl_xor(sy, off);
            sz += __shfl_xor(sz, off);
        }

        // scalar metadata (uniform addresses -> s_load)
        int nvA = nvox[p0], nvB = nvox[p0 + 1];
        nvA = nvA < 1 ? 1 : (nvA > NPTS ? NPTS : nvA);
        nvB = nvB < 1 ? 1 : (nvB > NPTS ? NPTS : nvB);
        const float cxA = (float)coors[p0 * 4 + 3] * 0.2f + 0.1f;
        const float cyA = (float)coors[p0 * 4 + 2] * 0.2f + (-39.9f);
        const float cxB = (float)coors[p0 * 4 + 7] * 0.2f + 0.1f;
        const float cyB = (float)coors[p0 * 4 + 6] * 0.2f + (-39.9f);
        const float iA  = 1.f / (float)nvA,  iB  = 1.f / (float)nvB;
        const float mA0 = __shfl(sx, 0)  * iA, mA1 = __shfl(sy, 0)  * iA, mA2 = __shfl(sz, 0)  * iA;
        const float mB0 = __shfl(sx, 32) * iB, mB1 = __shfl(sy, 32) * iB, mB2 = __shfl(sz, 32) * iB;
        const float bA = -(mA0 * w4 + mA1 * w5 + mA2 * w6 + cxA * w7 + cyA * w8);
        const float bB = -(mB0 * w4 + mB1 * w5 + mB2 * w6 + cxB * w7 + cyB * w8);

        // uniform point bases: whole wave reads the same point -> scalar loads
        const float* fpA = feat + (size_t)p0 * 128;
        const float* fpB = fpA + 128;

        float mA = -3.4e38f, mB = -3.4e38f;
        const int nmin = nvA < nvB ? nvA : nvB;

        #pragma unroll 4
        for (int n = 0; n < nmin; ++n) {
            const float4 a  = *reinterpret_cast<const float4*>(fpA + n * 4);
            const float4 b4 = *reinterpret_cast<const float4*>(fpB + n * 4);
            const float xA = fmaf(a.x,  wp0, fmaf(a.y,  wp1, fmaf(a.z,  wp2, fmaf(a.w,  wp3, bA))));
            const float xB = fmaf(b4.x, wp0, fmaf(b4.y, wp1, fmaf(b4.z, wp2, fmaf(b4.w, wp3, bB))));
            lsum += xA; lsq = fmaf(xA, xA, lsq); mA = fmaxf(mA, xA);
            lsum += xB; lsq = fmaf(xB, xB, lsq); mB = fmaxf(mB, xB);
        }
        #pragma unroll 4
        for (int n = nmin; n < nvA; ++n) {       // at most one tail loop runs
            const float4 a = *reinterpret_cast<const float4*>(fpA + n * 4);
            const float xA = fmaf(a.x, wp0, fmaf(a.y, wp1, fmaf(a.z, wp2, fmaf(a.w, wp3, bA))));
            lsum += xA; lsq = fmaf(xA, xA, lsq); mA = fmaxf(mA, xA);
        }
        #pragma unroll 4
        for (int n = nmin; n < nvB; ++n) {
            const float4 b4 = *reinterpret_cast<const float4*>(fpB + n * 4);
            const float xB = fmaf(b4.x, wp0, fmaf(b4.y, wp1, fmaf(b4.z, wp2, fmaf(b4.w, wp3, bB))));
            lsum += xB; lsq = fmaf(xB, xB, lsq); mB = fmaxf(mB, xB);
        }

        xext[(size_t)p0 * UNITS + lane]       = sg * mA;
        xext[(size_t)(p0 + 1) * UNITS + lane] = sg * mB;
    }

    ps[wave][lane]      = sg * lsum;   // Σx = sg * Σx'
    ps[wave][64 + lane] = lsq;         // x'^2 == x^2
    __syncthreads();
    if (tid < 128)
        partials[blockIdx.x * 128 + tid] = ps[0][tid] + ps[1][tid] + ps[2][tid] + ps[3][tid];
}

__global__ __launch_bounds__(256)
void pfn_finalize(const float* __restrict__ partials,
                  const float* __restrict__ gamma,
                  const float* __restrict__ beta,
                  float*       __restrict__ ss)
{
    const int u = blockIdx.x;   // 0..63
    const int t = threadIdx.x;  // 0..255
    double aS = 0.0, aQ = 0.0;
    for (int b = t; b < SBLOCKS; b += 256) {
        aS += (double)partials[b * 128 + u];
        aQ += (double)partials[b * 128 + 64 + u];
    }
    __shared__ double sS[256], sQ[256];
    sS[t] = aS; sQ[t] = aQ;
    __syncthreads();
    for (int s = 128; s > 0; s >>= 1) {
        if (t < s) { sS[t] += sS[t + s]; sQ[t] += sQ[t + s]; }
        __syncthreads();
    }
    if (t == 0) {
        const double inv_pn = 1.0 / ((double)PTOT * (double)NPTS);
        const double mean = sS[0] * inv_pn;
        const double var  = sQ[0] * inv_pn - mean * mean;
        const float scale = gamma[u] * (float)(1.0 / sqrt(var + 1e-3));
        const float shift = beta[u] - (float)mean * scale;
        ss[u]      = scale;
        ss[64 + u] = shift;
    }
}

// Kernel C: streaming apply, one float4 (4 consecutive units) per thread.
// out[p,u] = max( scale*ext+shift, [nv<32 ? max(shift,0) : 0] ) with relu floor.
#define CBLOCKS 2500   // 2500*256 threads * 4 floats = 2,560,000 exactly

__global__ __launch_bounds__(256)
void pfn_apply(const float4* __restrict__ xext,
               const int*    __restrict__ nvox,
               const float*  __restrict__ ss,
               float4*       __restrict__ out)
{
    const int i  = blockIdx.x * 256 + threadIdx.x;   // float4 index
    const int u0 = (i & 15) * 4;                     // first unit of this quad
    const int p  = i >> 4;                           // pillar
    const float4 sc = *reinterpret_cast<const float4*>(ss + u0);
    const float4 sh = *reinterpret_cast<const float4*>(ss + 64 + u0);
    const float4 e  = xext[i];
    const bool pad  = nvox[p] < NPTS;
    float4 o;
    o.x = fmaxf(fmaf(e.x, sc.x, sh.x), pad ? fmaxf(sh.x, 0.f) : 0.f);
    o.y = fmaxf(fmaf(e.y, sc.y, sh.y), pad ? fmaxf(sh.y, 0.f) : 0.f);
    o.z = fmaxf(fmaf(e.z, sc.z, sh.z), pad ? fmaxf(sh.z, 0.f) : 0.f);
    o.w = fmaxf(fmaf(e.w, sc.w, sh.w), pad ? fmaxf(sh.w, 0.f) : 0.f);
    out[i] = o;
}

extern "C" void kernel_launch(void* const* d_in, const int* in_sizes, int n_in,
                              void* d_out, int out_size, void* d_ws, size_t ws_size,
                              hipStream_t stream)
{
    const float* feat  = (const float*)d_in[0];
    const int*   nvox  = (const int*)d_in[1];
    const int*   coors = (const int*)d_in[2];
    const float* Wm    = (const float*)d_in[3];
    const float* gamma = (const float*)d_in[4];
    const float* beta  = (const float*)d_in[5];
    float* out = (float*)d_out;

    float* xext     = (float*)d_ws;                            // P*U floats = 10.24 MB
    float* partials = xext + (size_t)PTOT * UNITS;             // SBLOCKS*128 floats
    float* ss       = partials + (size_t)SBLOCKS * 128;        // 128 floats

    pfn_main<<<SBLOCKS, 256, 0, stream>>>(feat, nvox, coors, Wm, gamma, xext, partials);
    pfn_finalize<<<UNITS, 256, 0, stream>>>(partials, gamma, beta, ss);
    pfn_apply<<<CBLOCKS, 256, 0, stream>>>((const float4*)xext, nvox, ss, (float4*)out);
}